// Round 1
// baseline (345.452 us; speedup 1.0000x reference)
//
#include <hip/hip_runtime.h>
#include <hip/hip_bf16.h>
#include <stdint.h>

#define DIM 512
#define NROWS 1024
#define NCLS 100000
#define SCALE_S 64.0f
#define NBN 192
#define BM 256
#define BN 64
#define BK 64
#define NSTRIPE ((NCLS + BN - 1) / BN)   // 1563

typedef __attribute__((ext_vector_type(8))) __bf16 bf16x8;
typedef __attribute__((ext_vector_type(4))) float f32x4;
typedef __attribute__((ext_vector_type(4))) unsigned int u32x4;

__device__ __forceinline__ unsigned short f2bf(float x) {
  __hip_bfloat16 h = __float2bfloat16(x);
  union { __hip_bfloat16 h; unsigned short u; } v; v.h = h; return v.u;
}
__device__ __forceinline__ unsigned pack2(float a, float b) {
  return ((unsigned)f2bf(b) << 16) | (unsigned)f2bf(a);
}
__device__ __forceinline__ void async_ld16(const void* g, void* l) {
  __builtin_amdgcn_global_load_lds((const __attribute__((address_space(1))) void*)g,
                                   (__attribute__((address_space(3))) void*)l, 16, 0, 0);
}
// online-softmax merge: (m,s) <- merge((m,s),(m2,s2)), guards -inf/0 states
__device__ __forceinline__ void merge_ms(float& m, float& s, float m2, float s2) {
  float M = fmaxf(m, m2);
  float a = (s  > 0.f) ? s  * __expf(m  - M) : 0.f;
  float b = (s2 > 0.f) ? s2 * __expf(m2 - M) : 0.f;
  m = M; s = a + b;
}

// ---------------- kernel 1: normalize inputs -> bf16, save norms ----------------
__global__ void prep_kernel(const float* __restrict__ X, unsigned short* __restrict__ A16,
                            float* __restrict__ xnorm) {
  const int row = blockIdx.x;
  const int lane = threadIdx.x;  // 64
  const float4* xp = (const float4*)(X + (size_t)row * DIM);
  float4 v0 = xp[lane];
  float4 v1 = xp[lane + 64];
  float ss = v0.x*v0.x + v0.y*v0.y + v0.z*v0.z + v0.w*v0.w
           + v1.x*v1.x + v1.y*v1.y + v1.z*v1.z + v1.w*v1.w;
  #pragma unroll
  for (int m = 1; m < 64; m <<= 1) ss += __shfl_xor(ss, m);
  const float nrm = sqrtf(ss);
  const float inv = 1.0f / fmaxf(nrm, 1e-12f);
  if (lane == 0) xnorm[row] = nrm;
  unsigned short* ap = A16 + (size_t)row * DIM;
  *(uint2*)(ap + lane * 4)       = make_uint2(pack2(v0.x*inv, v0.y*inv), pack2(v0.z*inv, v0.w*inv));
  *(uint2*)(ap + 256 + lane * 4) = make_uint2(pack2(v1.x*inv, v1.y*inv), pack2(v1.z*inv, v1.w*inv));
}

// ---------------- kernel 2: fused GEMM + online logsumexp partials ----------------
// grid = NBN*4 blocks, 256 threads (4 waves). Block covers BM=256 rows x grid-strided
// BN=64-col stripes. W normalization folded in as per-column output scale (colSS).
__global__ __launch_bounds__(256) void gemm_lse_kernel(
    const unsigned short* __restrict__ A16, const float* __restrict__ Wg,
    float* __restrict__ part_m, float* __restrict__ part_s) {
  __shared__ unsigned short Alds[BM * BK];   // 32KB, XOR-swizzled content
  __shared__ unsigned short Wlds[BN * BK];   // 8KB, XOR-swizzled
  __shared__ float colSS[BN];
  __shared__ float red_m[BM];
  __shared__ float red_s[BM];

  const int tid  = threadIdx.x;
  const int lane = tid & 63;
  const int wave = tid >> 6;           // wave_m 0..3
  const int lr = lane & 15, lg = lane >> 4;
  const int bid = blockIdx.x;
  const int mblk = bid & 3;            // consecutive blocks share the same W stripes (L2/LLC)
  const int nblk = bid >> 2;           // 0..NBN-1
  const int mrow0 = mblk * BM;

  const int wj  = tid >> 2;            // 0..63: local W column this thread stages
  const int wkc = (tid & 3) * 16;      // k-chunk within BK

  float run_m = -INFINITY, run_s = 0.f;

  for (int s = nblk; s < NSTRIPE; s += NBN) {
    const int col0 = s * BN;
    __syncthreads();                   // prev stripe fully consumed
    if (tid < BN) colSS[tid] = 0.f;
    f32x4 acc[4][4];
    #pragma unroll
    for (int i = 0; i < 4; ++i)
      #pragma unroll
      for (int j = 0; j < 4; ++j) acc[i][j] = f32x4{0.f, 0.f, 0.f, 0.f};
    float wss = 0.f;
    int jg = col0 + wj; if (jg > NCLS - 1) jg = NCLS - 1;   // clamp tail (masked later)
    const float* wrow = Wg + (size_t)jg * DIM;
    const char* Abase = (const char*)(A16 + (size_t)mrow0 * DIM);

    for (int kt = 0; kt < DIM / BK; ++kt) {
      __syncthreads();                 // LDS tiles free
      // --- stage A (bf16, global_load_lds w=16, pre-swizzled source) ---
      #pragma unroll
      for (int it = 0; it < 8; ++it) {
        const int chunk = wave * 8 + it;          // 32 chunks x 1KB
        const int d = chunk * 1024 + lane * 16;   // linear LDS dest byte
        const int arow = d >> 7;                  // row (128B per row)
        const int kb = (d ^ ((arow & 7) << 4)) & 127;  // inverse-swizzled source byte
        async_ld16(Abase + (size_t)arow * 1024 + kt * 128 + kb,
                   (char*)Alds + chunk * 1024);
      }
      // --- stage W (f32 -> bf16 in reg, swizzled ds_write, accumulate colSS) ---
      {
        const float4* wp = (const float4*)(wrow + kt * BK + wkc);
        float4 f0 = wp[0], f1 = wp[1], f2 = wp[2], f3 = wp[3];
        wss += f0.x*f0.x + f0.y*f0.y + f0.z*f0.z + f0.w*f0.w
             + f1.x*f1.x + f1.y*f1.y + f1.z*f1.z + f1.w*f1.w
             + f2.x*f2.x + f2.y*f2.y + f2.z*f2.z + f2.w*f2.w
             + f3.x*f3.x + f3.y*f3.y + f3.z*f3.z + f3.w*f3.w;
        u32x4 w0, w1;
        w0.x = pack2(f0.x, f0.y); w0.y = pack2(f0.z, f0.w);
        w0.z = pack2(f1.x, f1.y); w0.w = pack2(f1.z, f1.w);
        w1.x = pack2(f2.x, f2.y); w1.y = pack2(f2.z, f2.w);
        w1.z = pack2(f3.x, f3.y); w1.w = pack2(f3.z, f3.w);
        const int base = wj * 128 + wkc * 2;
        const int swz = (wj & 7) << 4;
        *(u32x4*)((char*)Wlds + ((base)      ^ swz)) = w0;
        *(u32x4*)((char*)Wlds + ((base + 16) ^ swz)) = w1;
      }
      __syncthreads();                 // tiles ready (vmcnt+lgkm drained by barrier)
      // --- MFMA: 2 k-halves x 4x4 fragments ---
      #pragma unroll
      for (int kh = 0; kh < 2; ++kh) {
        bf16x8 af[4], bfr[4];
        #pragma unroll
        for (int mi = 0; mi < 4; ++mi) {
          const int ar = wave * 64 + mi * 16 + lr;
          int o = ar * 128 + kh * 64 + lg * 16;
          o ^= (ar & 7) << 4;
          af[mi] = *(const bf16x8*)((const char*)Alds + o);
        }
        #pragma unroll
        for (int ni = 0; ni < 4; ++ni) {
          const int bc = ni * 16 + lr;
          int o = bc * 128 + kh * 64 + lg * 16;
          o ^= (bc & 7) << 4;
          bfr[ni] = *(const bf16x8*)((const char*)Wlds + o);
        }
        #pragma unroll
        for (int mi = 0; mi < 4; ++mi)
          #pragma unroll
          for (int ni = 0; ni < 4; ++ni)
            acc[mi][ni] = __builtin_amdgcn_mfma_f32_16x16x32_bf16(af[mi], bfr[ni], acc[mi][ni], 0, 0, 0);
      }
    }
    atomicAdd(&colSS[wj], wss);        // 4 threads/column, LDS atomic
    __syncthreads();                   // colSS complete, MFMA done
    // --- epilogue: scale by 1/||w||, clip, S*, wave-parallel (max,sumexp) per row ---
    float invw[4]; int val[4];
    #pragma unroll
    for (int ni = 0; ni < 4; ++ni) {
      const int cl = ni * 16 + lr;
      invw[ni] = 1.0f / fmaxf(sqrtf(colSS[cl]), 1e-12f);
      val[ni] = (col0 + cl) < NCLS;
    }
    #pragma unroll
    for (int mi = 0; mi < 4; ++mi) {
      #pragma unroll
      for (int r = 0; r < 4; ++r) {
        float lv[4];
        #pragma unroll
        for (int ni = 0; ni < 4; ++ni) {
          float c = acc[mi][ni][r] * invw[ni];
          c = fminf(1.f, fmaxf(-1.f, c));
          lv[ni] = val[ni] ? SCALE_S * c : -INFINITY;
        }
        float mx = fmaxf(fmaxf(lv[0], lv[1]), fmaxf(lv[2], lv[3]));
        #pragma unroll
        for (int msk = 1; msk < 16; msk <<= 1) mx = fmaxf(mx, __shfl_xor(mx, msk));
        float sm = 0.f;
        #pragma unroll
        for (int ni = 0; ni < 4; ++ni) sm += val[ni] ? __expf(lv[ni] - mx) : 0.f;
        #pragma unroll
        for (int msk = 1; msk < 16; msk <<= 1) sm += __shfl_xor(sm, msk);
        if (lr == 0) {
          const int rl = wave * 64 + mi * 16 + lg * 4 + r;
          red_m[rl] = mx; red_s[rl] = sm;
        }
      }
    }
    __syncthreads();                   // red ready
    merge_ms(run_m, run_s, red_m[tid], red_s[tid]);   // thread tid owns row tid
  }
  part_m[(size_t)nblk * NROWS + mrow0 + tid] = run_m;
  part_s[(size_t)nblk * NROWS + mrow0 + tid] = run_s;
}

// ---------------- kernel 3: precise f32 target logit + merge partials ----------------
__global__ void finalize_kernel(const float* __restrict__ X, const int* __restrict__ labels,
                                const float* __restrict__ Wg, const float* __restrict__ xnorm,
                                const float* __restrict__ part_m, const float* __restrict__ part_s,
                                float* __restrict__ rowloss) {
  const int row = blockIdx.x;
  const int lane = threadIdx.x;   // 64
  const int lbl = labels[row];
  const float4* xp = (const float4*)(X + (size_t)row * DIM);
  const float4* wp = (const float4*)(Wg + (size_t)lbl * DIM);
  float dot = 0.f, wss = 0.f;
  #pragma unroll
  for (int i = 0; i < 2; ++i) {
    float4 xv = xp[lane + 64 * i];
    float4 wv = wp[lane + 64 * i];
    dot += xv.x*wv.x + xv.y*wv.y + xv.z*wv.z + xv.w*wv.w;
    wss += wv.x*wv.x + wv.y*wv.y + wv.z*wv.z + wv.w*wv.w;
  }
  #pragma unroll
  for (int m = 1; m < 64; m <<= 1) { dot += __shfl_xor(dot, m); wss += __shfl_xor(wss, m); }
  float m = -INFINITY, ssum = 0.f;
  #pragma unroll
  for (int i = 0; i < NBN / 64; ++i) {
    const int p = lane + 64 * i;
    merge_ms(m, ssum, part_m[(size_t)p * NROWS + row], part_s[(size_t)p * NROWS + row]);
  }
  #pragma unroll
  for (int msk = 1; msk < 64; msk <<= 1) {
    float m2 = __shfl_xor(m, msk), s2 = __shfl_xor(ssum, msk);
    merge_ms(m, ssum, m2, s2);
  }
  if (lane == 0) {
    float c = dot / (fmaxf(xnorm[row], 1e-12f) * fmaxf(sqrtf(wss), 1e-12f));
    c = fminf(1.f, fmaxf(-1.f, c));
    const float cm = 0.99500416527802576610f;   // cos(0.1)
    const float sn = 0.09983341664682815230f;   // sin(0.1)
    float unmod = SCALE_S * c;                  // the term the GEMM summed for the label col
    float modv  = SCALE_S * (c * cm - sqrtf(fmaxf(0.f, 1.f - c * c)) * sn); // S*cos(theta+m)
    float M = fmaxf(m, fmaxf(unmod, modv));
    float stot = ((ssum > 0.f) ? ssum * __expf(m - M) : 0.f)
               - __expf(unmod - M) + __expf(modv - M);
    stot = fmaxf(stot, 1e-30f);
    rowloss[row] = (logf(stot) + M) - modv;     // logsumexp - target logit
  }
}

// ---------------- kernel 4: mean over rows ----------------
__global__ void reduce_kernel(const float* __restrict__ rowloss, float* __restrict__ out) {
  const int tid = threadIdx.x;   // 256
  float s = 0.f;
  #pragma unroll
  for (int i = 0; i < 4; ++i) s += rowloss[tid + i * 256];
  #pragma unroll
  for (int m = 1; m < 64; m <<= 1) s += __shfl_xor(s, m);
  __shared__ float wsum[4];
  if ((tid & 63) == 0) wsum[tid >> 6] = s;
  __syncthreads();
  if (tid == 0) out[0] = (wsum[0] + wsum[1] + wsum[2] + wsum[3]) * (1.0f / NROWS);
}

extern "C" void kernel_launch(void* const* d_in, const int* in_sizes, int n_in,
                              void* d_out, int out_size, void* d_ws, size_t ws_size,
                              hipStream_t stream) {
  const float* X      = (const float*)d_in[0];
  const int*   labels = (const int*)d_in[1];
  const float* Wg     = (const float*)d_in[2];
  float* out = (float*)d_out;
  char* ws = (char*)d_ws;
  // ws layout (bytes): A16 1MB | xnorm 4KB | part_m 768KB | part_s 768KB | rowloss 4KB
  unsigned short* A16 = (unsigned short*)ws;
  float* xnorm   = (float*)(ws + 1048576);
  float* part_m  = (float*)(ws + 1048576 + 4096);
  float* part_s  = (float*)(ws + 1048576 + 4096 + (size_t)NBN * NROWS * 4);
  float* rowloss = (float*)(ws + 1048576 + 4096 + 2 * (size_t)NBN * NROWS * 4);

  prep_kernel<<<NROWS, 64, 0, stream>>>(X, A16, xnorm);
  gemm_lse_kernel<<<NBN * 4, 256, 0, stream>>>(A16, Wg, part_m, part_s);
  finalize_kernel<<<NROWS, 64, 0, stream>>>(X, labels, Wg, xnorm, part_m, part_s, rowloss);
  reduce_kernel<<<1, 256, 0, stream>>>(rowloss, out);
}

// Round 2
// 164.494 us; speedup vs baseline: 2.1001x; 2.1001x over previous
//
#include <hip/hip_runtime.h>
#include <hip/hip_bf16.h>
#include <stdint.h>

#define DIM 512
#define NROWS 1024
#define NCLS 100000
#define NCLS_PAD 100032
#define SCALE_S 64.0f
#define NBN 192                          // stripe columns of the grid (multiple of 8)
#define NSTRIPE ((NCLS + 63) / 64)       // 1563 stripes of 64 cols

typedef __attribute__((ext_vector_type(8))) __bf16 bf16x8;
typedef __attribute__((ext_vector_type(4))) float f32x4;

__device__ __forceinline__ unsigned short f2bf(float x) {
  __hip_bfloat16 h = __float2bfloat16(x);
  union { __hip_bfloat16 h; unsigned short u; } v; v.h = h; return v.u;
}
__device__ __forceinline__ unsigned pack2(float a, float b) {
  return ((unsigned)f2bf(b) << 16) | (unsigned)f2bf(a);
}
__device__ __forceinline__ void async_ld16(const void* g, void* l) {
  __builtin_amdgcn_global_load_lds((const __attribute__((address_space(1))) void*)g,
                                   (__attribute__((address_space(3))) void*)l, 16, 0, 0);
}

// ---------------- kernel 1a: normalize inputs -> bf16 ----------------
__global__ void prep_a(const float* __restrict__ X, unsigned short* __restrict__ A16,
                       float* __restrict__ xnorm) {
  const int row = blockIdx.x;
  const int lane = threadIdx.x;  // 64
  const float4* xp = (const float4*)(X + (size_t)row * DIM);
  float4 v0 = xp[lane];
  float4 v1 = xp[lane + 64];
  float ss = v0.x*v0.x + v0.y*v0.y + v0.z*v0.z + v0.w*v0.w
           + v1.x*v1.x + v1.y*v1.y + v1.z*v1.z + v1.w*v1.w;
  #pragma unroll
  for (int m = 1; m < 64; m <<= 1) ss += __shfl_xor(ss, m);
  const float nrm = sqrtf(ss);
  const float inv = 1.0f / fmaxf(nrm, 1e-12f);
  if (lane == 0) xnorm[row] = nrm;
  unsigned short* ap = A16 + (size_t)row * DIM;
  *(uint2*)(ap + lane * 4)       = make_uint2(pack2(v0.x*inv, v0.y*inv), pack2(v0.z*inv, v0.w*inv));
  *(uint2*)(ap + 256 + lane * 4) = make_uint2(pack2(v1.x*inv, v1.y*inv), pack2(v1.z*inv, v1.w*inv));
}

// ---------------- kernel 1b: normalize weight rows -> bf16 (padded to 100032) ----------------
__global__ void prep_w(const float* __restrict__ Wg, unsigned short* __restrict__ W16) {
  const int row = blockIdx.x * 4 + (threadIdx.x >> 6);
  const int lane = threadIdx.x & 63;
  unsigned short* op = W16 + (size_t)row * DIM;
  if (row >= NCLS) {                       // zero-pad tail rows
    *(uint4*)((char*)op + lane * 16) = make_uint4(0, 0, 0, 0);
    return;
  }
  const float4* xp = (const float4*)(Wg + (size_t)row * DIM);
  float4 v0 = xp[lane];
  float4 v1 = xp[lane + 64];
  float ss = v0.x*v0.x + v0.y*v0.y + v0.z*v0.z + v0.w*v0.w
           + v1.x*v1.x + v1.y*v1.y + v1.z*v1.z + v1.w*v1.w;
  #pragma unroll
  for (int m = 1; m < 64; m <<= 1) ss += __shfl_xor(ss, m);
  const float inv = 1.0f / fmaxf(sqrtf(ss), 1e-12f);
  *(uint2*)(op + lane * 4)       = make_uint2(pack2(v0.x*inv, v0.y*inv), pack2(v0.z*inv, v0.w*inv));
  *(uint2*)(op + 256 + lane * 4) = make_uint2(pack2(v1.x*inv, v1.y*inv), pack2(v1.z*inv, v1.w*inv));
}

// ---------------- kernel 2: deep-pipelined GEMM + fixed-max sumexp partials ----------------
// 256 threads (4 waves x 32 rows), BM=128, BN=64, BK=64. A-frags fully in registers.
// W staged via global_load_lds into an 8-buffer LDS ring, LOOKAHEAD=6 phases,
// steady s_waitcnt vmcnt(12) (counted, never 0 mid-loop). One barrier per phase.

__device__ __forceinline__ void stage_w(const char* W16g, char* wldsb, int buf, int ktp,
                                        int tcol0, int wave, int lane) {
  #pragma unroll
  for (int it = 0; it < 2; ++it) {
    const int d = (wave * 2 + it) * 1024 + lane * 16;   // linear dest byte in 8KB tile
    const int c = d >> 7;                                // col within stripe (128B per col-row)
    const int b = d & 127;
    // pre-swizzled global source so that swizzled ds_read sees logical bytes (G21)
    async_ld16(W16g + ((size_t)(tcol0 + c) * 1024 + ktp * 128 + (b ^ ((c & 7) << 4))),
               wldsb + buf * 8192 + (wave * 2 + it) * 1024);
  }
}

template<int KT>
__device__ __forceinline__ void mfma_phase(const char* wldsb, const bf16x8 (&af)[8][2][2],
                                           f32x4 (&acc)[2][4], int lr, int lg) {
  const char* wb = wldsb + KT * 8192;
  #pragma unroll
  for (int kh = 0; kh < 2; ++kh) {
    bf16x8 bfr[4];
    #pragma unroll
    for (int ni = 0; ni < 4; ++ni) {
      const int bc = ni * 16 + lr;
      const int o = (bc * 128 + kh * 64 + lg * 16) ^ ((bc & 7) << 4);
      bfr[ni] = *(const bf16x8*)(wb + o);
    }
    #pragma unroll
    for (int mi = 0; mi < 2; ++mi)
      #pragma unroll
      for (int ni = 0; ni < 4; ++ni)
        acc[mi][ni] = __builtin_amdgcn_mfma_f32_16x16x32_bf16(af[KT][kh][mi], bfr[ni], acc[mi][ni], 0, 0, 0);
  }
}

#define PHASE(KT, VMT)                                                              \
  do {                                                                              \
    if ((KT) < 2) {                                                                 \
      stage_w(W16g, wldsb, ((KT) + 6) & 7, (KT) + 6, col0, wave, lane);             \
      asm volatile("s_waitcnt vmcnt(12)" ::: "memory");                             \
    } else if (has_next) {                                                          \
      stage_w(W16g, wldsb, ((KT) + 6) & 7, (KT) - 2, ncol0, wave, lane);            \
      asm volatile("s_waitcnt vmcnt(12)" ::: "memory");                             \
    } else {                                                                        \
      asm volatile("s_waitcnt vmcnt(" #VMT ")" ::: "memory");                       \
    }                                                                               \
    __builtin_amdgcn_s_barrier();                                                   \
    mfma_phase<(KT)>(wldsb, af, acc, lr, lg);                                       \
  } while (0)

__global__ __launch_bounds__(256, 2) void gemm_lse2(
    const unsigned short* __restrict__ A16, const unsigned short* __restrict__ W16,
    float* __restrict__ part_s) {
  __shared__ char wlds[8 * 8192];          // 64 KB ring of 8 x 8KB W tiles
  char* wldsb = wlds;
  const char* W16g = (const char*)W16;

  const int tid = threadIdx.x;
  const int lane = tid & 63;
  const int wave = tid >> 6;
  const int lr = lane & 15, lg = lane >> 4;
  // bid = 64g + 8m + x : all 8 M-blocks of stripe-column (8g+x) share XCD x
  const int bid = blockIdx.x;
  const int mblk = (bid >> 3) & 7;
  const int nblk = ((bid >> 6) << 3) + (bid & 7);   // 0..191

  // ---- load all A fragments into registers (32 rows/wave x 512 K = 128 VGPR) ----
  bf16x8 af[8][2][2];
  {
    const char* Ab = (const char*)A16 + (size_t)(mblk * 128 + wave * 32) * 1024;
    #pragma unroll
    for (int kt = 0; kt < 8; ++kt)
      #pragma unroll
      for (int kh = 0; kh < 2; ++kh)
        #pragma unroll
        for (int mi = 0; mi < 2; ++mi)
          af[kt][kh][mi] = *(const bf16x8*)(Ab + (size_t)(mi * 16 + lr) * 1024 + kt * 128 + kh * 64 + lg * 16);
  }

  f32x4 acc[2][4];
  #pragma unroll
  for (int mi = 0; mi < 2; ++mi)
    #pragma unroll
    for (int ni = 0; ni < 4; ++ni) acc[mi][ni] = f32x4{0.f, 0.f, 0.f, 0.f};
  float srow[2][4];
  #pragma unroll
  for (int mi = 0; mi < 2; ++mi)
    #pragma unroll
    for (int r = 0; r < 4; ++r) srow[mi][r] = 0.f;

  // ---- prologue: stage phases 0..5 of first stripe ----
  {
    const int c0 = nblk * 64;
    #pragma unroll
    for (int pk = 0; pk < 6; ++pk) stage_w(W16g, wldsb, pk, pk, c0, wave, lane);
  }

  for (int s = nblk; s < NSTRIPE; s += NBN) {
    const int col0 = s * 64;
    const int ncol0 = (s + NBN) * 64;
    const bool has_next = (s + NBN) < NSTRIPE;

    PHASE(0, 12); PHASE(1, 12); PHASE(2, 10); PHASE(3, 8);
    PHASE(4, 6);  PHASE(5, 4);  PHASE(6, 2);  PHASE(7, 0);

    // ---- register-only epilogue: fixed max = S, accumulate sum of exp ----
    #pragma unroll
    for (int mi = 0; mi < 2; ++mi)
      #pragma unroll
      for (int ni = 0; ni < 4; ++ni) {
        const bool ok = (col0 + ni * 16 + lr) < NCLS;
        #pragma unroll
        for (int r = 0; r < 4; ++r) {
          float v = acc[mi][ni][r] * SCALE_S;
          v = fminf(SCALE_S, fmaxf(-SCALE_S, v));
          srow[mi][r] += ok ? __expf(v - SCALE_S) : 0.f;
          acc[mi][ni][r] = 0.f;
        }
      }
  }

  // ---- final per-row reduce over the 16 lr-lanes, write partials ----
  #pragma unroll
  for (int mi = 0; mi < 2; ++mi)
    #pragma unroll
    for (int r = 0; r < 4; ++r) {
      float v = srow[mi][r];
      v += __shfl_xor(v, 1); v += __shfl_xor(v, 2);
      v += __shfl_xor(v, 4); v += __shfl_xor(v, 8);
      if (lr == 0)
        part_s[(size_t)nblk * NROWS + mblk * 128 + wave * 32 + mi * 16 + lg * 4 + r] = v;
    }
}

// ---------------- kernel 3: precise f32 target logit + merge partials ----------------
__global__ void finalize_kernel(const float* __restrict__ X, const int* __restrict__ labels,
                                const float* __restrict__ Wg, const float* __restrict__ xnorm,
                                const float* __restrict__ part_s, float* __restrict__ rowloss) {
  const int row = blockIdx.x;
  const int lane = threadIdx.x;   // 64
  const int lbl = labels[row];
  const float4* xp = (const float4*)(X + (size_t)row * DIM);
  const float4* wp = (const float4*)(Wg + (size_t)lbl * DIM);
  float dot = 0.f, wss = 0.f;
  #pragma unroll
  for (int i = 0; i < 2; ++i) {
    float4 xv = xp[lane + 64 * i];
    float4 wv = wp[lane + 64 * i];
    dot += xv.x*wv.x + xv.y*wv.y + xv.z*wv.z + xv.w*wv.w;
    wss += wv.x*wv.x + wv.y*wv.y + wv.z*wv.z + wv.w*wv.w;
  }
  float psum = 0.f;
  #pragma unroll
  for (int i = 0; i < NBN / 64; ++i)
    psum += part_s[(size_t)(lane + 64 * i) * NROWS + row];
  #pragma unroll
  for (int m = 1; m < 64; m <<= 1) {
    dot += __shfl_xor(dot, m); wss += __shfl_xor(wss, m); psum += __shfl_xor(psum, m);
  }
  if (lane == 0) {
    float c = dot / (fmaxf(xnorm[row], 1e-12f) * fmaxf(sqrtf(wss), 1e-12f));
    c = fminf(1.f, fmaxf(-1.f, c));
    const float cm = 0.99500416527802576610f;   // cos(0.1)
    const float sn = 0.09983341664682815230f;   // sin(0.1)
    float unmod = SCALE_S * c;                  // term the GEMM summed at the label column
    float modv  = SCALE_S * (c * cm - sqrtf(fmaxf(0.f, 1.f - c * c)) * sn); // S*cos(theta+m)
    float stot = psum - __expf(unmod - SCALE_S) + __expf(modv - SCALE_S);
    stot = fmaxf(stot, 1e-37f);
    rowloss[row] = (logf(stot) + SCALE_S) - modv;   // logsumexp - target logit
  }
}

// ---------------- kernel 4: mean over rows ----------------
__global__ void reduce_kernel(const float* __restrict__ rowloss, float* __restrict__ out) {
  const int tid = threadIdx.x;   // 256
  float s = 0.f;
  #pragma unroll
  for (int i = 0; i < 4; ++i) s += rowloss[tid + i * 256];
  #pragma unroll
  for (int m = 1; m < 64; m <<= 1) s += __shfl_xor(s, m);
  __shared__ float wsum[4];
  if ((tid & 63) == 0) wsum[tid >> 6] = s;
  __syncthreads();
  if (tid == 0) out[0] = (wsum[0] + wsum[1] + wsum[2] + wsum[3]) * (1.0f / NROWS);
}

extern "C" void kernel_launch(void* const* d_in, const int* in_sizes, int n_in,
                              void* d_out, int out_size, void* d_ws, size_t ws_size,
                              hipStream_t stream) {
  const float* X      = (const float*)d_in[0];
  const int*   labels = (const int*)d_in[1];
  const float* Wg     = (const float*)d_in[2];
  float* out = (float*)d_out;
  char* ws = (char*)d_ws;
  // ws layout (bytes):
  //   A16    @ 0          1,048,576
  //   W16    @ 1,048,576  102,432,768   (100032 x 512 x 2B, rows >= NCLS zeroed)
  //   part_s @ 103,481,344   786,432    (NBN x 1024 x 4B)
  //   xnorm  @ 104,267,776     4,096
  //   rowloss@ 104,271,872     4,096
  unsigned short* A16 = (unsigned short*)ws;
  unsigned short* W16 = (unsigned short*)(ws + 1048576);
  float* part_s  = (float*)(ws + 103481344);
  float* xnorm   = (float*)(ws + 104267776);
  float* rowloss = (float*)(ws + 104271872);

  prep_a<<<NROWS, 64, 0, stream>>>(X, A16, xnorm);
  prep_w<<<NCLS_PAD / 4, 256, 0, stream>>>(Wg, W16);
  gemm_lse2<<<NBN * 8, 256, 0, stream>>>(A16, W16, part_s);
  finalize_kernel<<<NROWS, 64, 0, stream>>>(X, labels, Wg, xnorm, part_s, rowloss);
  reduce_kernel<<<1, 256, 0, stream>>>(rowloss, out);
}